// Round 9
// baseline (366.740 us; speedup 1.0000x reference)
//
#include <hip/hip_runtime.h>
#include <hip/hip_cooperative_groups.h>
#include <math.h>

namespace cg = cooperative_groups;

// Problem constants
#define CC 384
#define DD 768
#define TT 32
#define NN 196
#define BB 16
#define KK 16
#define NSAMP 500
#define JV 18816          // N*C/4 (float4 groups per frame)
#define FRAME 75264       // N*C

__device__ __forceinline__ float gelu_exact(float x) {
    return 0.5f * x * (1.0f + erff(x * 0.70710678118654752440f));
}

// ---------------- Kernel 1: mean+max pool over N, fused LayerNorm ----------------
__global__ __launch_bounds__(384) void pool_kernel(const float* __restrict__ x,
                                                   const float* __restrict__ ln_g,
                                                   const float* __restrict__ ln_b,
                                                   float* __restrict__ xbar) {
    int row = blockIdx.x;                       // b*T + t
    const float4* xp = (const float4*)(x + (size_t)row * NN * CC);
    int tx = threadIdx.x;                       // 0..95
    int ty = threadIdx.y;                       // 0..3
    float4 s = make_float4(0.f, 0.f, 0.f, 0.f);
    float4 m = make_float4(-INFINITY, -INFINITY, -INFINITY, -INFINITY);
    for (int n = ty; n < NN; n += 4) {
        float4 v = xp[n * 96 + tx];
        s.x += v.x; s.y += v.y; s.z += v.z; s.w += v.w;
        m.x = fmaxf(m.x, v.x); m.y = fmaxf(m.y, v.y);
        m.z = fmaxf(m.z, v.z); m.w = fmaxf(m.w, v.w);
    }
    __shared__ float4 ssum[4][96];
    __shared__ float4 smax[4][96];
    __shared__ float xf[DD];
    ssum[ty][tx] = s;
    smax[ty][tx] = m;
    __syncthreads();
    if (ty == 0) {
        for (int r = 1; r < 4; ++r) {
            float4 a = ssum[r][tx];
            s.x += a.x; s.y += a.y; s.z += a.z; s.w += a.w;
            float4 b = smax[r][tx];
            m.x = fmaxf(m.x, b.x); m.y = fmaxf(m.y, b.y);
            m.z = fmaxf(m.z, b.z); m.w = fmaxf(m.w, b.w);
        }
        const float invn = 1.0f / (float)NN;
        xf[4*tx+0] = s.x * invn; xf[4*tx+1] = s.y * invn;
        xf[4*tx+2] = s.z * invn; xf[4*tx+3] = s.w * invn;
        xf[CC + 4*tx+0] = m.x; xf[CC + 4*tx+1] = m.y;
        xf[CC + 4*tx+2] = m.z; xf[CC + 4*tx+3] = m.w;
    }
    __syncthreads();
    int tid = ty * 96 + tx;                     // 0..383
    float e0 = xf[tid], e1 = xf[tid + CC];
    float ps = e0 + e1, pq = e0 * e0 + e1 * e1;
    #pragma unroll
    for (int off = 32; off; off >>= 1) {
        ps += __shfl_down(ps, off);
        pq += __shfl_down(pq, off);
    }
    __shared__ float red[12];
    __shared__ float mv[2];
    int wv = tid >> 6;
    if ((tid & 63) == 0) { red[wv] = ps; red[6 + wv] = pq; }
    __syncthreads();
    if (tid == 0) {
        float su = 0.f, sq = 0.f;
        #pragma unroll
        for (int i = 0; i < 6; ++i) { su += red[i]; sq += red[6 + i]; }
        float mean = su * (1.0f / DD);
        float var  = sq * (1.0f / DD) - mean * mean;
        mv[0] = mean;
        mv[1] = rsqrtf(var + 1e-5f);
    }
    __syncthreads();
    float mean = mv[0], inv = mv[1];
    float* o = xbar + (size_t)row * DD;
    o[tid]      = (e0 - mean) * inv * ln_g[tid]      + ln_b[tid];
    o[tid + CC] = (e1 - mean) * inv * ln_g[tid + CC] + ln_b[tid + CC];
}

// ---------------- Kernel 2: FC_in partial GEMM, split-K=8 ----------------
// grid (64 rowg[8], 3 colg[256], 8 kc[96]), 256 threads.
__global__ __launch_bounds__(256) void fcinA_kernel(const float* __restrict__ xbar,
                                                    const float* __restrict__ w_in,
                                                    float* __restrict__ pfc) {
    __shared__ float xs[8][96];
    int tid = threadIdx.x;
    int row0 = blockIdx.x * 8;
    int col  = blockIdx.y * 256 + tid;
    int k0   = blockIdx.z * 96;
    if (tid < 192) {                       // stage 8 rows x 96 = 192 float4
        int r = tid / 24, j = tid % 24;
        ((float4*)xs[r])[j] = *(const float4*)(xbar + (size_t)(row0 + r) * DD + k0 + 4 * j);
    }
    __syncthreads();

    float acc[8] = {0.f, 0.f, 0.f, 0.f, 0.f, 0.f, 0.f, 0.f};
    const float* wp = w_in + (size_t)k0 * DD + col;
    #pragma unroll 2
    for (int i = 0; i < 96; i += 4) {
        float w0 = wp[(size_t)(i + 0) * DD];
        float w1 = wp[(size_t)(i + 1) * DD];
        float w2 = wp[(size_t)(i + 2) * DD];
        float w3 = wp[(size_t)(i + 3) * DD];
        #pragma unroll
        for (int r = 0; r < 8; ++r) {
            float4 xv = *(const float4*)&xs[r][i];
            acc[r] += xv.x * w0 + xv.y * w1 + xv.z * w2 + xv.w * w3;
        }
    }
    float* o = pfc + ((size_t)blockIdx.z * 512 + row0) * DD + col;
    #pragma unroll
    for (int r = 0; r < 8; ++r) o[(size_t)r * DD] = acc[r];
}

// ---------------- Kernel 3 (cooperative): fcinB + mlp1A/G + mlp1B + score + topk ----------
// grid 512 blocks x 256 threads, all co-resident; grid.sync() between phases.
__global__ __launch_bounds__(256) void predictor_kernel(const float* __restrict__ pfc,
                                                        const float* __restrict__ b_in,
                                                        const float* __restrict__ w1,
                                                        const float* __restrict__ b1,
                                                        const float* __restrict__ w2,
                                                        const float* __restrict__ b2,
                                                        const float* __restrict__ w3,
                                                        const float* __restrict__ noise,
                                                        float* __restrict__ h1,
                                                        float* __restrict__ pm1,
                                                        float* __restrict__ G,
                                                        float* __restrict__ h2,
                                                        float* __restrict__ scores,
                                                        float* __restrict__ ind) {
    cg::grid_group grid = cg::this_grid();
    __shared__ float xs[4][96];
    __shared__ float gs[CC];
    __shared__ float h2row[CC];
    __shared__ float ns[TT];
    __shared__ float mnmx[2];
    __shared__ float red[3];
    __shared__ int counts[KK * TT];
    int blk = blockIdx.x;      // 0..511
    int tid = threadIdx.x;     // 0..255

    // ---- P1: fcinB -> h1 (98304 float4 over 131072 threads) ----
    {
        int gid = blk * 256 + tid;
        if (gid < 98304) {
            int row = gid / 192, c4 = gid % 192;
            const float4* p4 = (const float4*)pfc;
            float4 s = ((const float4*)b_in)[c4];
            #pragma unroll
            for (int kc = 0; kc < 8; ++kc) {
                float4 v = p4[((size_t)kc * 512 + row) * 192 + c4];
                s.x += v.x; s.y += v.y; s.z += v.z; s.w += v.w;
            }
            float4 r;
            r.x = gelu_exact(s.x); r.y = gelu_exact(s.y);
            r.z = gelu_exact(s.z); r.w = gelu_exact(s.w);
            ((float4*)h1)[(size_t)row * 192 + c4] = r;
        }
    }
    grid.sync();

    // ---- P2: mlp1A local-half partial GEMM (1024 vb, 2 per block) + G tail ----
    #pragma unroll 1
    for (int rep = 0; rep < 2; ++rep) {
        __syncthreads();
        int vb = blk * 2 + rep;
        int kc = vb & 3, colg = (vb >> 2) & 1, rowg = vb >> 3;
        int row0 = rowg * 4, k0 = kc * 96;
        if (tid < 96) {
            int r = tid / 24, j = tid % 24;
            ((float4*)xs[r])[j] = *(const float4*)(h1 + (size_t)(row0 + r) * DD + k0 + 4 * j);
        }
        __syncthreads();
        if (tid < 192) {
            int col = colg * 192 + tid;
            float acc[4] = {0.f, 0.f, 0.f, 0.f};
            const float* wp = w1 + (size_t)k0 * CC + col;
            #pragma unroll 2
            for (int i = 0; i < 96; i += 4) {
                float w0 = wp[(size_t)(i + 0) * CC];
                float w1v = wp[(size_t)(i + 1) * CC];
                float w2v = wp[(size_t)(i + 2) * CC];
                float w3v = wp[(size_t)(i + 3) * CC];
                #pragma unroll
                for (int r = 0; r < 4; ++r) {
                    float4 xv = *(const float4*)&xs[r][i];
                    acc[r] += xv.x * w0 + xv.y * w1v + xv.z * w2v + xv.w * w3v;
                }
            }
            float* o = pm1 + ((size_t)kc * 512 + row0) * CC + col;
            #pragma unroll
            for (int r = 0; r < 4; ++r) o[(size_t)r * CC] = acc[r];
        }
    }
    if (blk < 32) {   // G tail: b = blk>>1, colg = blk&1
        int b = blk >> 1, colg = blk & 1;
        const float* hb = h1 + (size_t)b * TT * DD + CC;
        for (int i = tid; i < CC; i += 256) {
            float s = 0.f;
            #pragma unroll 8
            for (int t = 0; t < TT; ++t) s += hb[(size_t)t * DD + i];
            gs[i] = s * (1.0f / TT);
        }
        __syncthreads();
        if (tid < 192) {
            int col = colg * 192 + tid;
            float acc = 0.f;
            const float* wp = w1 + (size_t)CC * CC + col;
            #pragma unroll 8
            for (int i = 0; i < CC; ++i)
                acc += gs[i] * wp[(size_t)i * CC];
            G[b * CC + col] = acc;
        }
    }
    grid.sync();

    // ---- P3: mlp1B -> h2 (49152 float4) ----
    {
        int gid = blk * 256 + tid;
        if (gid < 49152) {
            int row = gid / 96, c4 = gid % 96;
            int b = row >> 5;
            const float4* p4 = (const float4*)pm1;
            float4 s = ((const float4*)b1)[c4];
            float4 gv = ((const float4*)G)[b * 96 + c4];
            s.x += gv.x; s.y += gv.y; s.z += gv.z; s.w += gv.w;
            #pragma unroll
            for (int kc = 0; kc < 4; ++kc) {
                float4 v = p4[((size_t)kc * 512 + row) * 96 + c4];
                s.x += v.x; s.y += v.y; s.z += v.z; s.w += v.w;
            }
            float4 r;
            r.x = gelu_exact(s.x); r.y = gelu_exact(s.y);
            r.z = gelu_exact(s.z); r.w = gelu_exact(s.w);
            ((float4*)h2)[(size_t)row * 96 + c4] = r;
        }
    }
    grid.sync();

    // ---- P4: score (one row per block) ----
    {
        int row = blk;
        if (tid < 96)
            ((float4*)h2row)[tid] = ((const float4*)(h2 + (size_t)row * CC))[tid];
        __syncthreads();
        if (tid < 192) {
            float a = b2[tid];
            const float* wp = w2 + tid;
            #pragma unroll 8
            for (int k = 0; k < CC; ++k)
                a += h2row[k] * wp[(size_t)k * 192];
            float v = gelu_exact(a) * w3[tid];
            #pragma unroll
            for (int off = 32; off; off >>= 1) v += __shfl_down(v, off);
            if ((tid & 63) == 0) red[tid >> 6] = v;
        }
        __syncthreads();
        if (tid == 0) scores[row] = red[0] + red[1] + red[2];  // b3 cancels in min-max
    }
    grid.sync();

    // ---- P5: min-max norm + perturbed top-k (blocks 0..15) ----
    if (blk < BB) {
        int b = blk;
        if (tid < TT) ns[tid] = scores[b * TT + tid];
        counts[tid] = 0;
        counts[tid + 256] = 0;
        __syncthreads();
        if (tid == 0) {
            float mn = ns[0], mx = ns[0];
            for (int t = 1; t < TT; ++t) { mn = fminf(mn, ns[t]); mx = fmaxf(mx, ns[t]); }
            mnmx[0] = mn; mnmx[1] = mx;
        }
        __syncthreads();
        if (tid < TT) ns[tid] = (ns[tid] - mnmx[0]) / (mnmx[1] - mnmx[0] + 1e-5f);
        __syncthreads();

        for (int smp = tid; smp < NSAMP; smp += 256) {
            const float* nb = noise + ((size_t)b * NSAMP + smp) * TT;
            float p[TT];
            #pragma unroll
            for (int t = 0; t < TT; ++t) p[t] = ns[t] + nb[t] * 0.05f;
            int k = 0;
            #pragma unroll
            for (int t = 0; t < TT; ++t) {
                int rank = 0;
                #pragma unroll
                for (int u = 0; u < TT; ++u)
                    rank += (p[u] > p[t] || (p[u] == p[t] && u < t)) ? 1 : 0;
                if (rank < KK) { atomicAdd(&counts[k * TT + t], 1); ++k; }
            }
        }
        __syncthreads();
        ind[b * (KK * TT) + tid]       = (float)counts[tid]       * (1.0f / NSAMP);
        ind[b * (KK * TT) + 256 + tid] = (float)counts[tid + 256] * (1.0f / NSAMP);
    }
}

// ---------------- Kernel 4: weighted gather with parallel active-frame compaction --------
__global__ __launch_bounds__(256) void gather_kernel(const float* __restrict__ x,
                                                     const float* __restrict__ ind,
                                                     float* __restrict__ out) {
    __shared__ float w[KK * TT];
    __shared__ int act[TT];
    __shared__ int nact_s;
    int b = blockIdx.y;
    int tid = threadIdx.x;
    w[tid] = ind[b * (KK * TT) + tid];
    w[256 + tid] = ind[b * (KK * TT) + 256 + tid];
    __syncthreads();
    if (tid < TT) {                     // wave-parallel compaction (wave 0 only)
        float s = 0.f;
        #pragma unroll
        for (int k = 0; k < KK; ++k) s += w[k * TT + tid];
        unsigned long long m = __ballot(s != 0.f);
        if (s != 0.f) act[__popcll(m & ((1ull << tid) - 1ull))] = tid;
        if (tid == 0) nact_s = (int)__popcll(m);
    }
    __syncthreads();
    int nact = nact_s;

    int j4 = blockIdx.x * 256 + tid;
    if (j4 >= JV) return;

    const float4* xb = (const float4*)(x + (size_t)b * TT * FRAME);
    float4 acc[KK];
    #pragma unroll
    for (int k = 0; k < KK; ++k) acc[k] = make_float4(0.f, 0.f, 0.f, 0.f);

    for (int it = 0; it < nact; ++it) {
        int t = act[it];
        float4 v = xb[(size_t)t * JV + j4];
        #pragma unroll
        for (int k = 0; k < KK; ++k) {
            float wk = w[k * TT + t];
            acc[k].x += wk * v.x; acc[k].y += wk * v.y;
            acc[k].z += wk * v.z; acc[k].w += wk * v.w;
        }
    }
    float4* ob = (float4*)(out + (size_t)b * KK * FRAME);
    #pragma unroll
    for (int k = 0; k < KK; ++k)
        ob[(size_t)k * JV + j4] = acc[k];
}

extern "C" void kernel_launch(void* const* d_in, const int* in_sizes, int n_in,
                              void* d_out, int out_size, void* d_ws, size_t ws_size,
                              hipStream_t stream) {
    const float* x     = (const float*)d_in[0];
    const float* noise = (const float*)d_in[1];
    const float* ln_g  = (const float*)d_in[2];
    const float* ln_b  = (const float*)d_in[3];
    const float* w_in  = (const float*)d_in[4];
    const float* b_in  = (const float*)d_in[5];
    const float* w1    = (const float*)d_in[6];
    const float* b1    = (const float*)d_in[7];
    const float* w2    = (const float*)d_in[8];
    const float* b2    = (const float*)d_in[9];
    const float* w3    = (const float*)d_in[10];
    const float* b3    = (const float*)d_in[11];
    (void)b3;  // cancels in min-max normalization
    float* out = (float*)d_out;

    float* ws     = (float*)d_ws;
    float* xbar   = ws;                       // 512*768 (LayerNorm'd)
    float* pfc    = xbar + 512 * DD;          // 8*512*768 partials
    float* h1     = pfc + 8 * 512 * DD;       // 512*768
    float* pm1    = h1 + 512 * DD;            // 4*512*384 partials
    float* h2     = pm1 + 4 * 512 * CC;       // 512*384
    float* G      = h2 + 512 * CC;            // 16*384
    float* scores = G + BB * CC;              // 512
    float* ind    = scores + 512;             // 16*512

    hipLaunchKernelGGL(pool_kernel, dim3(BB * TT), dim3(96, 4), 0, stream,
                       x, ln_g, ln_b, xbar);
    hipLaunchKernelGGL(fcinA_kernel, dim3(64, 3, 8), dim3(256), 0, stream,
                       xbar, w_in, pfc);

    void* args[] = {
        (void*)&pfc, (void*)&b_in, (void*)&w1, (void*)&b1,
        (void*)&w2, (void*)&b2, (void*)&w3, (void*)&noise,
        (void*)&h1, (void*)&pm1, (void*)&G, (void*)&h2,
        (void*)&scores, (void*)&ind
    };
    hipLaunchCooperativeKernel((const void*)predictor_kernel,
                               dim3(512), dim3(256), args, 0, stream);

    hipLaunchKernelGGL(gather_kernel, dim3((JV + 255) / 256, BB), dim3(256), 0, stream,
                       x, ind, out);
}

// Round 10
// 139.998 us; speedup vs baseline: 2.6196x; 2.6196x over previous
//
#include <hip/hip_runtime.h>
#include <math.h>

// Problem constants
#define CC 384
#define DD 768
#define TT 32
#define NN 196
#define BB 16
#define KK 16
#define NSAMP 500
#define JV 18816          // N*C/4 (float4 groups per frame)
#define FRAME 75264       // N*C

__device__ __forceinline__ float gelu_exact(float x) {
    return 0.5f * x * (1.0f + erff(x * 0.70710678118654752440f));
}

// ---------------- Kernel 1: mean+max pool over N, fused LayerNorm ----------------
__global__ __launch_bounds__(384) void pool_kernel(const float* __restrict__ x,
                                                   const float* __restrict__ ln_g,
                                                   const float* __restrict__ ln_b,
                                                   float* __restrict__ xbar) {
    int row = blockIdx.x;                       // b*T + t
    const float4* xp = (const float4*)(x + (size_t)row * NN * CC);
    int tx = threadIdx.x;                       // 0..95
    int ty = threadIdx.y;                       // 0..3
    float4 s = make_float4(0.f, 0.f, 0.f, 0.f);
    float4 m = make_float4(-INFINITY, -INFINITY, -INFINITY, -INFINITY);
    for (int n = ty; n < NN; n += 4) {
        float4 v = xp[n * 96 + tx];
        s.x += v.x; s.y += v.y; s.z += v.z; s.w += v.w;
        m.x = fmaxf(m.x, v.x); m.y = fmaxf(m.y, v.y);
        m.z = fmaxf(m.z, v.z); m.w = fmaxf(m.w, v.w);
    }
    __shared__ float4 ssum[4][96];
    __shared__ float4 smax[4][96];
    __shared__ float xf[DD];
    ssum[ty][tx] = s;
    smax[ty][tx] = m;
    __syncthreads();
    if (ty == 0) {
        for (int r = 1; r < 4; ++r) {
            float4 a = ssum[r][tx];
            s.x += a.x; s.y += a.y; s.z += a.z; s.w += a.w;
            float4 b = smax[r][tx];
            m.x = fmaxf(m.x, b.x); m.y = fmaxf(m.y, b.y);
            m.z = fmaxf(m.z, b.z); m.w = fmaxf(m.w, b.w);
        }
        const float invn = 1.0f / (float)NN;
        xf[4*tx+0] = s.x * invn; xf[4*tx+1] = s.y * invn;
        xf[4*tx+2] = s.z * invn; xf[4*tx+3] = s.w * invn;
        xf[CC + 4*tx+0] = m.x; xf[CC + 4*tx+1] = m.y;
        xf[CC + 4*tx+2] = m.z; xf[CC + 4*tx+3] = m.w;
    }
    __syncthreads();
    int tid = ty * 96 + tx;                     // 0..383
    float e0 = xf[tid], e1 = xf[tid + CC];
    float ps = e0 + e1, pq = e0 * e0 + e1 * e1;
    #pragma unroll
    for (int off = 32; off; off >>= 1) {
        ps += __shfl_down(ps, off);
        pq += __shfl_down(pq, off);
    }
    __shared__ float red[12];
    __shared__ float mv[2];
    int wv = tid >> 6;
    if ((tid & 63) == 0) { red[wv] = ps; red[6 + wv] = pq; }
    __syncthreads();
    if (tid == 0) {
        float su = 0.f, sq = 0.f;
        #pragma unroll
        for (int i = 0; i < 6; ++i) { su += red[i]; sq += red[6 + i]; }
        float mean = su * (1.0f / DD);
        float var  = sq * (1.0f / DD) - mean * mean;
        mv[0] = mean;
        mv[1] = rsqrtf(var + 1e-5f);
    }
    __syncthreads();
    float mean = mv[0], inv = mv[1];
    float* o = xbar + (size_t)row * DD;
    o[tid]      = (e0 - mean) * inv * ln_g[tid]      + ln_b[tid];
    o[tid + CC] = (e1 - mean) * inv * ln_g[tid + CC] + ln_b[tid + CC];
}

// ---------------- Kernel 2: FC_in with IN-BLOCK split-K, writes h1 directly ----------------
// grid (128 rowg[4], 3 colg[256]) x 1024 threads. 4 k-groups of 192 each.
__global__ __launch_bounds__(1024) void fcin_kernel(const float* __restrict__ xbar,
                                                    const float* __restrict__ w_in,
                                                    const float* __restrict__ b_in,
                                                    float* __restrict__ h1) {
    __shared__ float xs[4][DD];          // 12 KB: 4 rows x 768 (LayerNorm'd input)
    __shared__ float pacc[4][4][256];    // 16 KB: [kg][row][col]
    int tid = threadIdx.x;
    int row0 = blockIdx.x * 4;
    int col0 = blockIdx.y * 256;

    if (tid < 768) {                     // stage 4 rows x 192 float4
        int r = tid / 192, j = tid % 192;
        ((float4*)xs[r])[j] = *(const float4*)(xbar + (size_t)(row0 + r) * DD + 4 * j);
    }
    __syncthreads();

    int kg = tid >> 8;                   // 0..3
    int c  = tid & 255;
    int col = col0 + c;
    int k0 = kg * 192;
    float a0 = 0.f, a1 = 0.f, a2 = 0.f, a3 = 0.f;
    const float* wp = w_in + (size_t)k0 * DD + col;
    #pragma unroll 4
    for (int i = 0; i < 192; ++i) {
        float wv = wp[(size_t)i * DD];
        a0 += xs[0][k0 + i] * wv;        // wave-uniform LDS broadcast
        a1 += xs[1][k0 + i] * wv;
        a2 += xs[2][k0 + i] * wv;
        a3 += xs[3][k0 + i] * wv;
    }
    pacc[kg][0][c] = a0; pacc[kg][1][c] = a1;
    pacc[kg][2][c] = a2; pacc[kg][3][c] = a3;
    __syncthreads();

    int rr = tid >> 8;                   // row this thread reduces
    float s = b_in[col] + pacc[0][rr][c] + pacc[1][rr][c]
                        + pacc[2][rr][c] + pacc[3][rr][c];
    h1[(size_t)(row0 + rr) * DD + col] = gelu_exact(s);
}

// ---------------- Kernel 3: global pool + global-half GEMM -> G[b][col] ----------------
// grid (16 b, 3 colg[128]), 128 threads.
__global__ __launch_bounds__(128) void gpoolG_kernel(const float* __restrict__ h1,
                                                     const float* __restrict__ w1,
                                                     float* __restrict__ G) {
    __shared__ float gs[CC];
    int tid = threadIdx.x;
    int b = blockIdx.x;
    const float* hb = h1 + (size_t)b * TT * DD + CC;
    for (int i = tid; i < CC; i += 128) {
        float s = 0.f;
        #pragma unroll 8
        for (int t = 0; t < TT; ++t) s += hb[(size_t)t * DD + i];
        gs[i] = s * (1.0f / TT);
    }
    __syncthreads();
    int col = blockIdx.y * 128 + tid;
    float acc = 0.f;
    const float* wp = w1 + (size_t)CC * CC + col;   // rows 384.. of w1
    #pragma unroll 8
    for (int i = 0; i < CC; ++i)
        acc += gs[i] * wp[(size_t)i * CC];
    G[b * CC + col] = acc;
}

// ---------------- Kernel 4: mlp1 with IN-BLOCK split-K, writes h2 directly ----------------
// grid (128 rowg[4], 2 colg[192]) x 768 threads. 4 k-groups of 96 each (local half);
// global half enters via precomputed G.
__global__ __launch_bounds__(768) void mlp1_kernel(const float* __restrict__ h1,
                                                   const float* __restrict__ G,
                                                   const float* __restrict__ w1,
                                                   const float* __restrict__ b1,
                                                   float* __restrict__ h2) {
    __shared__ float xs[4][CC];          // 6 KB: 4 rows x 384 (local half)
    __shared__ float pacc[4][4][192];    // 12 KB
    int tid = threadIdx.x;
    int row0 = blockIdx.x * 4;
    int col0 = blockIdx.y * 192;
    int b = row0 >> 5;

    if (tid < 384) {                     // 4 rows x 96 float4
        int r = tid / 96, j = tid % 96;
        ((float4*)xs[r])[j] = *(const float4*)(h1 + (size_t)(row0 + r) * DD + 4 * j);
    }
    __syncthreads();

    int kg = tid / 192;                  // 0..3
    int c  = tid % 192;
    int col = col0 + c;
    int k0 = kg * 96;
    float a0 = 0.f, a1 = 0.f, a2 = 0.f, a3 = 0.f;
    const float* wp = w1 + (size_t)k0 * CC + col;
    #pragma unroll 4
    for (int i = 0; i < 96; ++i) {
        float wv = wp[(size_t)i * CC];
        a0 += xs[0][k0 + i] * wv;
        a1 += xs[1][k0 + i] * wv;
        a2 += xs[2][k0 + i] * wv;
        a3 += xs[3][k0 + i] * wv;
    }
    pacc[kg][0][c] = a0; pacc[kg][1][c] = a1;
    pacc[kg][2][c] = a2; pacc[kg][3][c] = a3;
    __syncthreads();

    int rr = tid / 192;
    float s = b1[col] + G[b * CC + col]
            + pacc[0][rr][c] + pacc[1][rr][c] + pacc[2][rr][c] + pacc[3][rr][c];
    h2[(size_t)(row0 + rr) * CC + col] = gelu_exact(s);
}

// ---------------- Kernel 5: per-row mlp2 GEMM -> scores ----------------
// grid 512 (one (b,t) row per block), 192 threads, h2 row staged in LDS.
__global__ __launch_bounds__(192) void score_kernel(const float* __restrict__ h2,
                                                    const float* __restrict__ w2,
                                                    const float* __restrict__ b2,
                                                    const float* __restrict__ w3,
                                                    float* __restrict__ scores) {
    __shared__ float h2row[CC];
    int row = blockIdx.x, tid = threadIdx.x;

    if (tid < 96)
        ((float4*)h2row)[tid] = ((const float4*)(h2 + (size_t)row * CC))[tid];
    __syncthreads();

    float a = b2[tid];
    const float* wp = w2 + tid;
    #pragma unroll 8
    for (int k = 0; k < CC; ++k)
        a += h2row[k] * wp[(size_t)k * 192];        // LDS broadcast * coalesced w2
    float v = gelu_exact(a) * w3[tid];
    #pragma unroll
    for (int off = 32; off; off >>= 1) v += __shfl_down(v, off);
    __shared__ float red[3];
    if ((tid & 63) == 0) red[tid >> 6] = v;
    __syncthreads();
    if (tid == 0) scores[row] = red[0] + red[1] + red[2];  // b3 cancels in min-max
}

// ---------------- Kernel 6: min-max norm + perturbed top-k -> indicators ----------------
__global__ __launch_bounds__(512) void topk_kernel(const float* __restrict__ scores,
                                                   const float* __restrict__ noise,
                                                   float* __restrict__ ind) {
    __shared__ float ns[TT];
    __shared__ float mnmx[2];
    __shared__ int counts[KK * TT];
    int b = blockIdx.x, tid = threadIdx.x;

    if (tid < TT) ns[tid] = scores[b * TT + tid];
    counts[tid] = 0;
    __syncthreads();
    if (tid == 0) {
        float mn = ns[0], mx = ns[0];
        for (int t = 1; t < TT; ++t) { mn = fminf(mn, ns[t]); mx = fmaxf(mx, ns[t]); }
        mnmx[0] = mn; mnmx[1] = mx;
    }
    __syncthreads();
    if (tid < TT) ns[tid] = (ns[tid] - mnmx[0]) / (mnmx[1] - mnmx[0] + 1e-5f);
    __syncthreads();

    if (tid < NSAMP) {
        const float* nb = noise + ((size_t)b * NSAMP + tid) * TT;
        float p[TT];
        #pragma unroll
        for (int t = 0; t < TT; ++t) p[t] = ns[t] + nb[t] * 0.05f;
        int k = 0;
        #pragma unroll
        for (int t = 0; t < TT; ++t) {
            int rank = 0;
            #pragma unroll
            for (int u = 0; u < TT; ++u)
                rank += (p[u] > p[t] || (p[u] == p[t] && u < t)) ? 1 : 0;
            if (rank < KK) { atomicAdd(&counts[k * TT + t], 1); ++k; }
        }
    }
    __syncthreads();
    ind[b * (KK * TT) + tid] = (float)counts[tid] * (1.0f / NSAMP);
}

// ---------------- Kernel 7: weighted gather with parallel active-frame compaction --------
__global__ __launch_bounds__(256) void gather_kernel(const float* __restrict__ x,
                                                     const float* __restrict__ ind,
                                                     float* __restrict__ out) {
    __shared__ float w[KK * TT];
    __shared__ int act[TT];
    __shared__ int nact_s;
    int b = blockIdx.y;
    int tid = threadIdx.x;
    w[tid] = ind[b * (KK * TT) + tid];
    w[256 + tid] = ind[b * (KK * TT) + 256 + tid];
    __syncthreads();
    if (tid < TT) {                     // wave-parallel compaction (wave 0 only)
        float s = 0.f;
        #pragma unroll
        for (int k = 0; k < KK; ++k) s += w[k * TT + tid];
        unsigned long long m = __ballot(s != 0.f);
        if (s != 0.f) act[__popcll(m & ((1ull << tid) - 1ull))] = tid;
        if (tid == 0) nact_s = (int)__popcll(m);
    }
    __syncthreads();
    int nact = nact_s;

    int j4 = blockIdx.x * 256 + tid;
    if (j4 >= JV) return;

    const float4* xb = (const float4*)(x + (size_t)b * TT * FRAME);
    float4 acc[KK];
    #pragma unroll
    for (int k = 0; k < KK; ++k) acc[k] = make_float4(0.f, 0.f, 0.f, 0.f);

    for (int it = 0; it < nact; ++it) {
        int t = act[it];
        float4 v = xb[(size_t)t * JV + j4];
        #pragma unroll
        for (int k = 0; k < KK; ++k) {
            float wk = w[k * TT + t];
            acc[k].x += wk * v.x; acc[k].y += wk * v.y;
            acc[k].z += wk * v.z; acc[k].w += wk * v.w;
        }
    }
    float4* ob = (float4*)(out + (size_t)b * KK * FRAME);
    #pragma unroll
    for (int k = 0; k < KK; ++k)
        ob[(size_t)k * JV + j4] = acc[k];
}

extern "C" void kernel_launch(void* const* d_in, const int* in_sizes, int n_in,
                              void* d_out, int out_size, void* d_ws, size_t ws_size,
                              hipStream_t stream) {
    const float* x     = (const float*)d_in[0];
    const float* noise = (const float*)d_in[1];
    const float* ln_g  = (const float*)d_in[2];
    const float* ln_b  = (const float*)d_in[3];
    const float* w_in  = (const float*)d_in[4];
    const float* b_in  = (const float*)d_in[5];
    const float* w1    = (const float*)d_in[6];
    const float* b1    = (const float*)d_in[7];
    const float* w2    = (const float*)d_in[8];
    const float* b2    = (const float*)d_in[9];
    const float* w3    = (const float*)d_in[10];
    const float* b3    = (const float*)d_in[11];
    (void)b3;  // cancels in min-max normalization
    float* out = (float*)d_out;

    float* ws     = (float*)d_ws;
    float* xbar   = ws;                       // 512*768 (LayerNorm'd)
    float* h1     = xbar + 512 * DD;          // 512*768
    float* h2     = h1 + 512 * DD;            // 512*384
    float* G      = h2 + 512 * CC;            // 16*384
    float* scores = G + BB * CC;              // 512
    float* ind    = scores + 512;             // 16*512

    hipLaunchKernelGGL(pool_kernel, dim3(BB * TT), dim3(96, 4), 0, stream,
                       x, ln_g, ln_b, xbar);
    hipLaunchKernelGGL(fcin_kernel, dim3(128, 3), dim3(1024), 0, stream,
                       xbar, w_in, b_in, h1);
    hipLaunchKernelGGL(gpoolG_kernel, dim3(BB, 3), dim3(128), 0, stream,
                       h1, w1, G);
    hipLaunchKernelGGL(mlp1_kernel, dim3(128, 2), dim3(768), 0, stream,
                       h1, G, w1, b1, h2);
    hipLaunchKernelGGL(score_kernel, dim3(512), dim3(192), 0, stream,
                       h2, w2, b2, w3, scores);
    hipLaunchKernelGGL(topk_kernel, dim3(BB), dim3(512), 0, stream,
                       scores, noise, ind);
    hipLaunchKernelGGL(gather_kernel, dim3((JV + 255) / 256, BB), dim3(256), 0, stream,
                       x, ind, out);
}

// Round 11
// 118.078 us; speedup vs baseline: 3.1059x; 1.1856x over previous
//
#include <hip/hip_runtime.h>
#include <math.h>

// Problem constants
#define CC 384
#define DD 768
#define TT 32
#define NN 196
#define BB 16
#define KK 16
#define NSAMP 500
#define JV 18816          // N*C/4 (float4 groups per frame)
#define FRAME 75264       // N*C

__device__ __forceinline__ float gelu_exact(float x) {
    return 0.5f * x * (1.0f + erff(x * 0.70710678118654752440f));
}

// ---------------- Kernel 1: mean+max pool over N, fused LayerNorm ----------------
__global__ __launch_bounds__(384) void pool_kernel(const float* __restrict__ x,
                                                   const float* __restrict__ ln_g,
                                                   const float* __restrict__ ln_b,
                                                   float* __restrict__ xbar) {
    int row = blockIdx.x;                       // b*T + t
    const float4* xp = (const float4*)(x + (size_t)row * NN * CC);
    int tx = threadIdx.x;                       // 0..95
    int ty = threadIdx.y;                       // 0..3
    float4 s = make_float4(0.f, 0.f, 0.f, 0.f);
    float4 m = make_float4(-INFINITY, -INFINITY, -INFINITY, -INFINITY);
    for (int n = ty; n < NN; n += 4) {
        float4 v = xp[n * 96 + tx];
        s.x += v.x; s.y += v.y; s.z += v.z; s.w += v.w;
        m.x = fmaxf(m.x, v.x); m.y = fmaxf(m.y, v.y);
        m.z = fmaxf(m.z, v.z); m.w = fmaxf(m.w, v.w);
    }
    __shared__ float4 ssum[4][96];
    __shared__ float4 smax[4][96];
    __shared__ float xf[DD];
    ssum[ty][tx] = s;
    smax[ty][tx] = m;
    __syncthreads();
    if (ty == 0) {
        for (int r = 1; r < 4; ++r) {
            float4 a = ssum[r][tx];
            s.x += a.x; s.y += a.y; s.z += a.z; s.w += a.w;
            float4 b = smax[r][tx];
            m.x = fmaxf(m.x, b.x); m.y = fmaxf(m.y, b.y);
            m.z = fmaxf(m.z, b.z); m.w = fmaxf(m.w, b.w);
        }
        const float invn = 1.0f / (float)NN;
        xf[4*tx+0] = s.x * invn; xf[4*tx+1] = s.y * invn;
        xf[4*tx+2] = s.z * invn; xf[4*tx+3] = s.w * invn;
        xf[CC + 4*tx+0] = m.x; xf[CC + 4*tx+1] = m.y;
        xf[CC + 4*tx+2] = m.z; xf[CC + 4*tx+3] = m.w;
    }
    __syncthreads();
    int tid = ty * 96 + tx;                     // 0..383
    float e0 = xf[tid], e1 = xf[tid + CC];
    float ps = e0 + e1, pq = e0 * e0 + e1 * e1;
    #pragma unroll
    for (int off = 32; off; off >>= 1) {
        ps += __shfl_down(ps, off);
        pq += __shfl_down(pq, off);
    }
    __shared__ float red[12];
    __shared__ float mv[2];
    int wv = tid >> 6;
    if ((tid & 63) == 0) { red[wv] = ps; red[6 + wv] = pq; }
    __syncthreads();
    if (tid == 0) {
        float su = 0.f, sq = 0.f;
        #pragma unroll
        for (int i = 0; i < 6; ++i) { su += red[i]; sq += red[6 + i]; }
        float mean = su * (1.0f / DD);
        float var  = sq * (1.0f / DD) - mean * mean;
        mv[0] = mean;
        mv[1] = rsqrtf(var + 1e-5f);
    }
    __syncthreads();
    float mean = mv[0], inv = mv[1];
    float* o = xbar + (size_t)row * DD;
    o[tid]      = (e0 - mean) * inv * ln_g[tid]      + ln_b[tid];
    o[tid + CC] = (e1 - mean) * inv * ln_g[tid + CC] + ln_b[tid + CC];
}

// ---------------- Kernel 2: FC_in, in-block split-K, float4 LDS reads ----------------
// grid (128 rowg[4], 3 colg[256]) x 1024 threads. Writes h1 AND Gpart (per-rowg
// column sums of gelu'd global half, for the downstream T-pool).
__global__ __launch_bounds__(1024) void fcin_kernel(const float* __restrict__ xbar,
                                                    const float* __restrict__ w_in,
                                                    const float* __restrict__ b_in,
                                                    float* __restrict__ h1,
                                                    float* __restrict__ Gpart) {
    __shared__ float xs[4][DD];          // 12 KB
    __shared__ float pacc[4][4][256];    // 16 KB
    int tid = threadIdx.x;
    int rowg = blockIdx.x;
    int row0 = rowg * 4;
    int col0 = blockIdx.y * 256;

    if (tid < 768) {                     // stage 4 rows x 192 float4
        int r = tid / 192, j = tid % 192;
        ((float4*)xs[r])[j] = *(const float4*)(xbar + (size_t)(row0 + r) * DD + 4 * j);
    }
    __syncthreads();

    int kg = tid >> 8;                   // 0..3
    int c  = tid & 255;
    int col = col0 + c;
    int k0 = kg * 192;
    float a0 = 0.f, a1 = 0.f, a2 = 0.f, a3 = 0.f;
    const float* wp = w_in + (size_t)k0 * DD + col;
    #pragma unroll 2
    for (int i = 0; i < 192; i += 4) {
        float w0 = wp[(size_t)(i + 0) * DD];
        float w1v = wp[(size_t)(i + 1) * DD];
        float w2v = wp[(size_t)(i + 2) * DD];
        float w3v = wp[(size_t)(i + 3) * DD];
        float4 x0 = *(const float4*)&xs[0][k0 + i];
        float4 x1 = *(const float4*)&xs[1][k0 + i];
        float4 x2 = *(const float4*)&xs[2][k0 + i];
        float4 x3 = *(const float4*)&xs[3][k0 + i];
        a0 += x0.x * w0 + x0.y * w1v + x0.z * w2v + x0.w * w3v;
        a1 += x1.x * w0 + x1.y * w1v + x1.z * w2v + x1.w * w3v;
        a2 += x2.x * w0 + x2.y * w1v + x2.z * w2v + x2.w * w3v;
        a3 += x3.x * w0 + x3.y * w1v + x3.z * w2v + x3.w * w3v;
    }
    pacc[kg][0][c] = a0; pacc[kg][1][c] = a1;
    pacc[kg][2][c] = a2; pacc[kg][3][c] = a3;
    __syncthreads();

    int rr = tid >> 8;                   // row this thread reduces
    float s = b_in[col] + pacc[0][rr][c] + pacc[1][rr][c]
                        + pacc[2][rr][c] + pacc[3][rr][c];
    float g = gelu_exact(s);
    h1[(size_t)(row0 + rr) * DD + col] = g;
    pacc[0][rr][c] = g;                  // stash (same-thread slot; safe)
    __syncthreads();

    if (rr == 0 && col >= CC) {          // one writer per (rowg, global col)
        float gsum = pacc[0][0][c] + pacc[0][1][c] + pacc[0][2][c] + pacc[0][3][c];
        Gpart[(size_t)rowg * CC + (col - CC)] = gsum;
    }
}

// ---------------- Kernel 3: mlp1, in-block split-K, inline global-half via Gpart ----------
// grid (128 rowg[4], 2 colg[192]) x 768 threads. 4 k-groups of 96 each over BOTH halves.
__global__ __launch_bounds__(768) void mlp1_kernel(const float* __restrict__ h1,
                                                   const float* __restrict__ Gpart,
                                                   const float* __restrict__ w1,
                                                   const float* __restrict__ b1,
                                                   float* __restrict__ h2) {
    __shared__ float xs[4][CC];          // 6 KB (local halves of 4 rows)
    __shared__ float gs[CC];             // 1.5 KB (T-pooled global half for this batch)
    __shared__ float pacc[4][5][192];    // 15 KB ([kg][row0..3 local | 4=global][col])
    int tid = threadIdx.x;
    int rowg = blockIdx.x;
    int row0 = rowg * 4;
    int b = row0 >> 5;
    int col0 = blockIdx.y * 192;

    if (tid < CC) {                      // gs[i] = sum of 8 rowg partials / 32
        float s = 0.f;
        const float* gp = Gpart + (size_t)(b * 8) * CC + tid;
        #pragma unroll
        for (int rg = 0; rg < 8; ++rg) s += gp[(size_t)rg * CC];
        gs[tid] = s * (1.0f / 32.0f);
    } else {                             // stage 4 rows x 96 float4 (local half)
        int e = tid - CC;
        int r = e / 96, j = e % 96;
        ((float4*)xs[r])[j] = *(const float4*)(h1 + (size_t)(row0 + r) * DD + 4 * j);
    }
    __syncthreads();

    int kg = tid / 192;                  // 0..3
    int c  = tid % 192;
    int col = col0 + c;
    int k0 = kg * 96;
    float a0 = 0.f, a1 = 0.f, a2 = 0.f, a3 = 0.f, ag = 0.f;
    const float* wl = w1 + (size_t)k0 * CC + col;          // local-half rows
    const float* wg = w1 + (size_t)(CC + k0) * CC + col;   // global-half rows
    #pragma unroll 2
    for (int i = 0; i < 96; i += 4) {
        float l0 = wl[(size_t)(i + 0) * CC];
        float l1 = wl[(size_t)(i + 1) * CC];
        float l2 = wl[(size_t)(i + 2) * CC];
        float l3 = wl[(size_t)(i + 3) * CC];
        float g0 = wg[(size_t)(i + 0) * CC];
        float g1 = wg[(size_t)(i + 1) * CC];
        float g2 = wg[(size_t)(i + 2) * CC];
        float g3 = wg[(size_t)(i + 3) * CC];
        float4 x0 = *(const float4*)&xs[0][k0 + i];
        float4 x1 = *(const float4*)&xs[1][k0 + i];
        float4 x2 = *(const float4*)&xs[2][k0 + i];
        float4 x3 = *(const float4*)&xs[3][k0 + i];
        float4 gv = *(const float4*)&gs[k0 + i];
        a0 += x0.x * l0 + x0.y * l1 + x0.z * l2 + x0.w * l3;
        a1 += x1.x * l0 + x1.y * l1 + x1.z * l2 + x1.w * l3;
        a2 += x2.x * l0 + x2.y * l1 + x2.z * l2 + x2.w * l3;
        a3 += x3.x * l0 + x3.y * l1 + x3.z * l2 + x3.w * l3;
        ag += gv.x * g0 + gv.y * g1 + gv.z * g2 + gv.w * g3;
    }
    pacc[kg][0][c] = a0; pacc[kg][1][c] = a1;
    pacc[kg][2][c] = a2; pacc[kg][3][c] = a3;
    pacc[kg][4][c] = ag;
    __syncthreads();

    int rr = tid / 192;                  // 0..3 (768 threads)
    float s = b1[col];
    #pragma unroll
    for (int kk = 0; kk < 4; ++kk)
        s += pacc[kk][rr][c] + pacc[kk][4][c];
    h2[(size_t)(row0 + rr) * CC + col] = gelu_exact(s);
}

// ---------------- Kernel 4: per-row mlp2 GEMM -> scores ----------------
// grid 512 (one (b,t) row per block), 192 threads, h2 row staged in LDS.
__global__ __launch_bounds__(192) void score_kernel(const float* __restrict__ h2,
                                                    const float* __restrict__ w2,
                                                    const float* __restrict__ b2,
                                                    const float* __restrict__ w3,
                                                    float* __restrict__ scores) {
    __shared__ float h2row[CC];
    int row = blockIdx.x, tid = threadIdx.x;

    if (tid < 96)
        ((float4*)h2row)[tid] = ((const float4*)(h2 + (size_t)row * CC))[tid];
    __syncthreads();

    float a = b2[tid];
    const float* wp = w2 + tid;
    #pragma unroll 8
    for (int k = 0; k < CC; ++k)
        a += h2row[k] * wp[(size_t)k * 192];        // LDS broadcast * coalesced w2
    float v = gelu_exact(a) * w3[tid];
    #pragma unroll
    for (int off = 32; off; off >>= 1) v += __shfl_down(v, off);
    __shared__ float red[3];
    if ((tid & 63) == 0) red[tid >> 6] = v;
    __syncthreads();
    if (tid == 0) scores[row] = red[0] + red[1] + red[2];  // b3 cancels in min-max
}

// ---------------- Kernel 5: min-max norm + perturbed top-k -> indicators ----------------
__global__ __launch_bounds__(512) void topk_kernel(const float* __restrict__ scores,
                                                   const float* __restrict__ noise,
                                                   float* __restrict__ ind) {
    __shared__ float ns[TT];
    __shared__ float mnmx[2];
    __shared__ int counts[KK * TT];
    int b = blockIdx.x, tid = threadIdx.x;

    if (tid < TT) ns[tid] = scores[b * TT + tid];
    counts[tid] = 0;
    __syncthreads();
    if (tid == 0) {
        float mn = ns[0], mx = ns[0];
        for (int t = 1; t < TT; ++t) { mn = fminf(mn, ns[t]); mx = fmaxf(mx, ns[t]); }
        mnmx[0] = mn; mnmx[1] = mx;
    }
    __syncthreads();
    if (tid < TT) ns[tid] = (ns[tid] - mnmx[0]) / (mnmx[1] - mnmx[0] + 1e-5f);
    __syncthreads();

    if (tid < NSAMP) {
        const float* nb = noise + ((size_t)b * NSAMP + tid) * TT;
        float p[TT];
        #pragma unroll
        for (int t = 0; t < TT; ++t) p[t] = ns[t] + nb[t] * 0.05f;
        int k = 0;
        #pragma unroll
        for (int t = 0; t < TT; ++t) {
            int rank = 0;
            #pragma unroll
            for (int u = 0; u < TT; ++u)
                rank += (p[u] > p[t] || (p[u] == p[t] && u < t)) ? 1 : 0;
            if (rank < KK) { atomicAdd(&counts[k * TT + t], 1); ++k; }
        }
    }
    __syncthreads();
    ind[b * (KK * TT) + tid] = (float)counts[tid] * (1.0f / NSAMP);
}

// ---------------- Kernel 6: weighted gather with parallel active-frame compaction --------
__global__ __launch_bounds__(256) void gather_kernel(const float* __restrict__ x,
                                                     const float* __restrict__ ind,
                                                     float* __restrict__ out) {
    __shared__ float w[KK * TT];
    __shared__ int act[TT];
    __shared__ int nact_s;
    int b = blockIdx.y;
    int tid = threadIdx.x;
    w[tid] = ind[b * (KK * TT) + tid];
    w[256 + tid] = ind[b * (KK * TT) + 256 + tid];
    __syncthreads();
    if (tid < TT) {                     // wave-parallel compaction (wave 0 only)
        float s = 0.f;
        #pragma unroll
        for (int k = 0; k < KK; ++k) s += w[k * TT + tid];
        unsigned long long m = __ballot(s != 0.f);
        if (s != 0.f) act[__popcll(m & ((1ull << tid) - 1ull))] = tid;
        if (tid == 0) nact_s = (int)__popcll(m);
    }
    __syncthreads();
    int nact = nact_s;

    int j4 = blockIdx.x * 256 + tid;
    if (j4 >= JV) return;

    const float4* xb = (const float4*)(x + (size_t)b * TT * FRAME);
    float4 acc[KK];
    #pragma unroll
    for (int k = 0; k < KK; ++k) acc[k] = make_float4(0.f, 0.f, 0.f, 0.f);

    for (int it = 0; it < nact; ++it) {
        int t = act[it];
        float4 v = xb[(size_t)t * JV + j4];
        #pragma unroll
        for (int k = 0; k < KK; ++k) {
            float wk = w[k * TT + t];
            acc[k].x += wk * v.x; acc[k].y += wk * v.y;
            acc[k].z += wk * v.z; acc[k].w += wk * v.w;
        }
    }
    float4* ob = (float4*)(out + (size_t)b * KK * FRAME);
    #pragma unroll
    for (int k = 0; k < KK; ++k)
        ob[(size_t)k * JV + j4] = acc[k];
}

extern "C" void kernel_launch(void* const* d_in, const int* in_sizes, int n_in,
                              void* d_out, int out_size, void* d_ws, size_t ws_size,
                              hipStream_t stream) {
    const float* x     = (const float*)d_in[0];
    const float* noise = (const float*)d_in[1];
    const float* ln_g  = (const float*)d_in[2];
    const float* ln_b  = (const float*)d_in[3];
    const float* w_in  = (const float*)d_in[4];
    const float* b_in  = (const float*)d_in[5];
    const float* w1    = (const float*)d_in[6];
    const float* b1    = (const float*)d_in[7];
    const float* w2    = (const float*)d_in[8];
    const float* b2    = (const float*)d_in[9];
    const float* w3    = (const float*)d_in[10];
    const float* b3    = (const float*)d_in[11];
    (void)b3;  // cancels in min-max normalization
    float* out = (float*)d_out;

    float* ws     = (float*)d_ws;
    float* xbar   = ws;                       // 512*768 (LayerNorm'd)
    float* h1     = xbar + 512 * DD;          // 512*768
    float* Gpart  = h1 + 512 * DD;            // 128*384 per-rowg global-half sums
    float* h2     = Gpart + 128 * CC;         // 512*384
    float* scores = h2 + 512 * CC;            // 512
    float* ind    = scores + 512;             // 16*512

    hipLaunchKernelGGL(pool_kernel, dim3(BB * TT), dim3(96, 4), 0, stream,
                       x, ln_g, ln_b, xbar);
    hipLaunchKernelGGL(fcin_kernel, dim3(128, 3), dim3(1024), 0, stream,
                       xbar, w_in, b_in, h1, Gpart);
    hipLaunchKernelGGL(mlp1_kernel, dim3(128, 2), dim3(768), 0, stream,
                       h1, Gpart, w1, b1, h2);
    hipLaunchKernelGGL(score_kernel, dim3(512), dim3(192), 0, stream,
                       h2, w2, b2, w3, scores);
    hipLaunchKernelGGL(topk_kernel, dim3(BB), dim3(512), 0, stream,
                       scores, noise, ind);
    hipLaunchKernelGGL(gather_kernel, dim3((JV + 255) / 256, BB), dim3(256), 0, stream,
                       x, ind, out);
}